// Round 18
// baseline (347.686 us; speedup 1.0000x reference)
//
#include <hip/hip_runtime.h>

// SpikeFFN: out = spike(LIF(x @ W1^T)) @ W2^T ; T=4 B=8 N=1024 C=512, fp32.
//
// HARD CONSTRAINT (r8): GEMM1 = single full-K ascending serial FMA chain per
// output in fp32 (np reference arithmetic); v_fma_f32 == CPU vfmadd.
// Tiling/load order free; per-output chain order is not.
//
// r13: B s_load (SMEM): OOO lgkm drains cap VALU at 66% -> 197us. Best so far.
// r15: VMEM-B 1-deep ring: fits (52 VGPR) but 64cyc cover vs 250cyc L2
//      latency -> 44% VALU, 339us.
// r16: 4-deep ring BUT full unroll of the group loop -> 32 hoisted loads ->
//      live-range explosion -> spill (FETCH 3.8GB, 4.8% VALU), 2898us.
// r17: r16 with #pragma unroll 1 on the group loop (the only change that
//      matters): 4-deep ring = 192 FMA-cyc in flight >= L2 latency, counted
//      vmcnt waits, DS alone on lgkm, demand ~100 VGPR under the 128 cap.

typedef _Float16 half8  __attribute__((ext_vector_type(8)));
typedef _Float16 half4v __attribute__((ext_vector_type(4)));
typedef float    f32x4  __attribute__((ext_vector_type(4)));
typedef unsigned short ushort8 __attribute__((ext_vector_type(8)));

constexpr int TT   = 4;
constexpr int BB   = 8;
constexpr int NN   = 1024;
constexpr int CC   = 512;                 // Cin == Cout
constexpr int MROW = BB * NN;             // 8192 rows per timestep
constexpr int MTOT = TT * MROW;           // 32768 rows total
constexpr int BNC  = MROW * CC;           // per-timestep elems
constexpr int LDK  = 40;                  // fp16 LDS stride (gemm2)
constexpr int LTA  = 260;                 // fp32 LDS row stride (256+4 pad)

// --------------------------- W1 -> Wt[k][o] transpose ----------------------
__global__ __launch_bounds__(256)
void transpose_w(const float* __restrict__ W, float* __restrict__ Wt) {
    __shared__ float T[64][65];
    const int tid = threadIdx.x;
    const int bo  = blockIdx.x * 64;   // o tile
    const int bk  = blockIdx.y * 64;   // k tile
#pragma unroll
    for (int j = 0; j < 16; ++j) {
        int id = tid + 256 * j;
        int r = id >> 6, c = id & 63;              // r: o, c: k
        T[r][c] = W[(size_t)(bo + r) * CC + bk + c];
    }
    __syncthreads();
#pragma unroll
    for (int j = 0; j < 16; ++j) {
        int id = tid + 256 * j;
        int r = id >> 6, c = id & 63;              // r: k, c: o
        Wt[(size_t)(bk + r) * CC + bo + c] = T[c][r];
    }
}

// ---------- GEMM1: single full-K ascending serial FMA chain (fp32) ---------
// 256x64 block tile, 512 threads (8 waves x 8 cols), 4x8 outputs/thread.
// A in dbuf LDS (contiguous b128 lane reads, lgkm = DS only);
// B from Wt via VMEM broadcast loads, 4-deep named-register ring,
// group loop NOT unrolled (r16 lesson: full unroll -> live-range explosion).
__global__ __launch_bounds__(512, 4)
void gemm1_v17(const float* __restrict__ X, const float* __restrict__ Wt,
               float* __restrict__ H) {
#pragma clang fp contract(off)
    __shared__ float At[2][32][LTA];   // 66.5 KB

    const int tid  = threadIdx.x;
    const int lane = tid & 63;
    const int wid  = tid >> 6;                    // 0..7
    const int RM   = blockIdx.x * 256;
    const int CN   = blockIdx.y * 64 + wid * 8;   // wave col base
    const float* wcol = Wt + CN;                  // Wt[gk][CN..CN+7]

    const int srow = tid >> 1;           // staging row 0..255
    const int sk16 = (tid & 1) * 16;     // staging k base (0 or 16)

    float acc[4][8] = {};                // ONE accumulator per output
    f32x4 rx[4];                         // A staging prefetch
    f32x4 b0a, b0b, b1a, b1b, b2a, b2b, b3a, b3b;   // 4-deep B ring

    // prologue: stage A tile 0; preload B rows gk = 0..3
#pragma unroll
    for (int q = 0; q < 4; ++q)
        rx[q] = *(const f32x4*)&X[(size_t)(RM + srow) * CC + sk16 + q * 4];
#pragma unroll
    for (int q = 0; q < 4; ++q)
#pragma unroll
        for (int e = 0; e < 4; ++e)
            At[0][sk16 + q * 4 + e][srow] = rx[q][e];
    b0a = *(const f32x4*)&wcol[0 * (size_t)CC];
    b0b = *(const f32x4*)&wcol[0 * (size_t)CC + 4];
    b1a = *(const f32x4*)&wcol[1 * (size_t)CC];
    b1b = *(const f32x4*)&wcol[1 * (size_t)CC + 4];
    b2a = *(const f32x4*)&wcol[2 * (size_t)CC];
    b2b = *(const f32x4*)&wcol[2 * (size_t)CC + 4];
    b3a = *(const f32x4*)&wcol[3 * (size_t)CC];
    b3b = *(const f32x4*)&wcol[3 * (size_t)CC + 4];
    __syncthreads();

#define FMA_K(kk, BA, BB_)                                                  \
    {                                                                       \
        f32x4 a = *(const f32x4*)&At[cur][kk][lane * 4];                    \
        _Pragma("unroll")                                                   \
        for (int i = 0; i < 4; ++i) {                                       \
            _Pragma("unroll")                                               \
            for (int e = 0; e < 4; ++e) {                                   \
                acc[i][e]     = __builtin_fmaf(a[i], BA[e], acc[i][e]);     \
                acc[i][4 + e] = __builtin_fmaf(a[i], BB_[e], acc[i][4 + e]);\
            }                                                               \
        }                                                                   \
    }

    for (int kt = 0; kt < 16; ++kt) {
        const int cur = kt & 1;
        // issue A loads for tile kt+1 (land under this tile's FMAs)
        if (kt < 15) {
            int kk = (kt + 1) * 32;
#pragma unroll
            for (int q = 0; q < 4; ++q)
                rx[q] = *(const f32x4*)&X[(size_t)(RM + srow) * CC + kk + sk16 + q * 4];
        }
        // FMA phase: strict ascending k; ring slot consumed then reloaded
        // for gk+4 (rows 512..515 of Wt are garbage pads, loaded, unused).
#pragma unroll 1
        for (int k = 0; k < 32; k += 4) {
            const size_t g4 = (size_t)(kt * 32 + k + 4) * CC;
            FMA_K(k, b0a, b0b)
            b0a = *(const f32x4*)&wcol[g4];
            b0b = *(const f32x4*)&wcol[g4 + 4];
            FMA_K(k + 1, b1a, b1b)
            b1a = *(const f32x4*)&wcol[g4 + CC];
            b1b = *(const f32x4*)&wcol[g4 + CC + 4];
            FMA_K(k + 2, b2a, b2b)
            b2a = *(const f32x4*)&wcol[g4 + 2 * CC];
            b2b = *(const f32x4*)&wcol[g4 + 2 * CC + 4];
            FMA_K(k + 3, b3a, b3b)
            b3a = *(const f32x4*)&wcol[g4 + 3 * CC];
            b3b = *(const f32x4*)&wcol[g4 + 3 * CC + 4];
        }
        // stage tile kt+1, one barrier pair per tile
        if (kt < 15) {
            __syncthreads();
#pragma unroll
            for (int q = 0; q < 4; ++q)
#pragma unroll
                for (int e = 0; e < 4; ++e)
                    At[cur ^ 1][sk16 + q * 4 + e][srow] = rx[q][e];
            __syncthreads();
        }
    }
#undef FMA_K

#pragma unroll
    for (int i = 0; i < 4; ++i) {
        size_t base = (size_t)(RM + lane * 4 + i) * CC + CN;
        f32x4 o0 = {acc[i][0], acc[i][1], acc[i][2], acc[i][3]};
        f32x4 o1 = {acc[i][4], acc[i][5], acc[i][6], acc[i][7]};
        *(f32x4*)&H[base]     = o0;
        *(f32x4*)&H[base + 4] = o1;
    }
}

// ----------------------------- LIF (fp32, np-op-exact) ---------------------
// Spike byte: 0x3C (= high byte of fp16 1.0) or 0x00.
__global__ __launch_bounds__(256)
void lif_np(const float* __restrict__ H, unsigned char* __restrict__ S8) {
#pragma clang fp contract(off)
    int g = blockIdx.x * 256 + threadIdx.x;   // 0 .. BNC/4-1
    float v[4] = {0.f, 0.f, 0.f, 0.f};
#pragma unroll
    for (int t = 0; t < TT; ++t) {
        f32x4 h = *(const f32x4*)&H[(size_t)t * BNC + (size_t)g * 4];
        unsigned int pack = 0;
#pragma unroll
        for (int e = 0; e < 4; ++e) {
            float d  = h[e] - v[e];          // rounded sub (np: x - (v-0))
            float d2 = d * 0.5f;             // exact (np: /2.0)
            v[e] = v[e] + d2;                // rounded add
            bool sp = v[e] >= 1.0f;
            if (sp) { pack |= 0x3Cu << (8 * e); v[e] = 0.0f; }
        }
        *(unsigned int*)&S8[(size_t)t * BNC + (size_t)g * 4] = pack;
    }
}

// ---------------------------------------------------------------- GEMM2 ----
// O[m][p] = sum_o S[m][o] * W2[p][o]. fp16 MFMA; spikes exact in fp16.
__global__ __launch_bounds__(256)
void gemm2_f16(const unsigned char* __restrict__ S8, const float* __restrict__ W,
               float* __restrict__ O) {
    __shared__ _Float16 As[128][LDK], Bs[128][LDK];

    const int tid  = threadIdx.x;
    const int RM   = blockIdx.x * 128;
    const int CN   = blockIdx.y * 128;
    const int lane = tid & 63;
    const int wv   = tid >> 6;
    const int wr   = (wv >> 1) * 64;
    const int wc   = (wv & 1) * 64;
    const int r15  = lane & 15;
    const int kg   = lane >> 4;

    f32x4 acc[4][4] = {};

    for (int k0 = 0; k0 < CC; k0 += 32) {
        __syncthreads();
#pragma unroll
        for (int j = 0; j < 2; ++j) {
            int id  = tid + 256 * j;
            int row = id >> 2;
            int c8  = (id & 3) * 8;
            unsigned long long v =
                *(const unsigned long long*)&S8[(size_t)(RM + row) * CC + k0 + c8];
            ushort8 u;
#pragma unroll
            for (int e = 0; e < 8; ++e)
                u[e] = (unsigned short)(((v >> (8 * e)) & 0xFFull) << 8);
            *(ushort8*)&As[row][c8] = u;
        }
#pragma unroll
        for (int j = 0; j < 4; ++j) {
            int id  = tid + 256 * j;
            int row = id >> 3;
            int c4  = (id & 7) * 4;
            f32x4 v = *(const f32x4*)&W[(size_t)(CN + row) * CC + k0 + c4];
            half4v hv;
#pragma unroll
            for (int e = 0; e < 4; ++e) hv[e] = (_Float16)v[e];
            *(half4v*)&Bs[row][c4] = hv;
        }
        __syncthreads();

        half8 a[4], b[4];
#pragma unroll
        for (int i = 0; i < 4; ++i) {
            a[i] = *(const half8*)&As[wr + i * 16 + r15][kg * 8];
            b[i] = *(const half8*)&Bs[wc + i * 16 + r15][kg * 8];
        }
#pragma unroll
        for (int i = 0; i < 4; ++i)
#pragma unroll
            for (int j = 0; j < 4; ++j)
                acc[i][j] = __builtin_amdgcn_mfma_f32_16x16x32_f16(a[i], b[j], acc[i][j], 0, 0, 0);
    }

#pragma unroll
    for (int i = 0; i < 4; ++i)
#pragma unroll
        for (int j = 0; j < 4; ++j)
#pragma unroll
            for (int r = 0; r < 4; ++r) {
                int gm = RM + wr + i * 16 + kg * 4 + r;
                int gn = CN + wc + j * 16 + r15;
                O[(size_t)gm * CC + gn] = acc[i][j][r];
            }
}

// -------------------------------------------------------------- launch -----
extern "C" void kernel_launch(void* const* d_in, const int* in_sizes, int n_in,
                              void* d_out, int out_size, void* d_ws, size_t ws_size,
                              hipStream_t stream) {
    const float* x  = (const float*)d_in[0];
    const float* W1 = (const float*)d_in[1];
    const float* W2 = (const float*)d_in[2];
    float* out = (float*)d_out;

    float*         h  = out;                                   // fp32 h in d_out
    unsigned char* s8 = (unsigned char*)d_ws;                  // spikes, 16 MB
    float*         wt = (float*)((char*)d_ws + (size_t)BNC);   // Wt, 512+4 rows

    dim3 gt(CC / 64, CC / 64);       // (8, 8)
    transpose_w<<<gt, 256, 0, stream>>>(W1, wt);

    dim3 g1(MTOT / 256, CC / 64);    // (128, 8) = 1024 blocks
    gemm1_v17<<<g1, 512, 0, stream>>>(x, wt, h);

    lif_np<<<BNC / 4 / 256, 256, 0, stream>>>(h, s8);

    dim3 g2(MTOT / 128, CC / 128);   // (256, 4)
    gemm2_f16<<<g2, 256, 0, stream>>>(s8, W2, out);
}

// Round 19
// 301.617 us; speedup vs baseline: 1.1527x; 1.1527x over previous
//
#include <hip/hip_runtime.h>

// SpikeFFN: out = spike(LIF(x @ W1^T)) @ W2^T ; T=4 B=8 N=1024 C=512, fp32.
//
// HARD CONSTRAINT (r8): GEMM1 = single full-K ascending serial FMA chain per
// output in fp32 (np reference arithmetic); v_fma_f32 == CPU vfmadd.
// Tiling/load order free; per-output chain order is not.
//
// History: r13 (s_load B + LDS A, 2 blocks/CU) = 197us @ 66% VALU (lgkm
// drains). r14-r17 VMEM-register-ring B: spill or insufficient depth ->
// 339-5368us. Dead end at this register budget.
// r19: keep r13's fragment scheme, crank TLP to hide the drains:
//   - 64-col wave panel -> acc[4][8]=32, demand ~50 VGPR <= 64 cap
//   - __launch_bounds__(512,8): 8 waves/SIMD
//   - single-buffer LDS (33.3 KB) -> 4 blocks/CU (133 KB, 2048 thr)
//   - grid (128,8) = 1024 blocks = 4/CU exactly
// A stalled wave's lgkmcnt(0) is covered by 31 other resident waves.

typedef _Float16 half8  __attribute__((ext_vector_type(8)));
typedef _Float16 half4v __attribute__((ext_vector_type(4)));
typedef float    f32x4  __attribute__((ext_vector_type(4)));
typedef float    f32x8  __attribute__((ext_vector_type(8)));
typedef unsigned short ushort8 __attribute__((ext_vector_type(8)));

constexpr int TT   = 4;
constexpr int BB   = 8;
constexpr int NN   = 1024;
constexpr int CC   = 512;                 // Cin == Cout
constexpr int MROW = BB * NN;             // 8192 rows per timestep
constexpr int MTOT = TT * MROW;           // 32768 rows total
constexpr int BNC  = MROW * CC;           // per-timestep elems
constexpr int LDK  = 40;                  // fp16 LDS stride (gemm2)
constexpr int LTA  = 260;                 // fp32 LDS row stride (256+4 pad)

// --------------------------- W1 -> Wt[k][o] transpose ----------------------
__global__ __launch_bounds__(256)
void transpose_w(const float* __restrict__ W, float* __restrict__ Wt) {
    __shared__ float T[64][65];
    const int tid = threadIdx.x;
    const int bo  = blockIdx.x * 64;   // o tile
    const int bk  = blockIdx.y * 64;   // k tile
#pragma unroll
    for (int j = 0; j < 16; ++j) {
        int id = tid + 256 * j;
        int r = id >> 6, c = id & 63;              // r: o, c: k
        T[r][c] = W[(size_t)(bo + r) * CC + bk + c];
    }
    __syncthreads();
#pragma unroll
    for (int j = 0; j < 16; ++j) {
        int id = tid + 256 * j;
        int r = id >> 6, c = id & 63;              // r: k, c: o
        Wt[(size_t)(bk + r) * CC + bo + c] = T[c][r];
    }
}

// ---------- GEMM1: single full-K ascending serial FMA chain (fp32) ---------
// 256x64 block tile, 512 threads (8 waves x 8 cols), 4x8 outputs/thread.
// A: single-buffer LDS, k-transposed, lane reads contiguous b128.
// B: wave-uniform s_load (f32x8) from Wt (readfirstlane'd wave col base).
__global__ __launch_bounds__(512, 8)
void gemm1_v19(const float* __restrict__ X, const float* __restrict__ Wt,
               float* __restrict__ H) {
#pragma clang fp contract(off)
    __shared__ float At[32][LTA];   // 33.3 KB -> 4 blocks/CU

    const int tid  = threadIdx.x;
    const int lane = tid & 63;
    const int wid  = __builtin_amdgcn_readfirstlane(tid >> 6);  // 0..7 uniform
    const int RM   = blockIdx.x * 256;
    const int CN   = blockIdx.y * 64 + wid * 8;   // wave col base (uniform)
    const float* wcol = Wt + CN;                  // Wt[gk][CN..CN+7]

    const int srow = tid >> 1;           // staging row 0..255
    const int sk16 = (tid & 1) * 16;     // staging k base (0 or 16)

    float acc[4][8] = {};                // ONE accumulator per output
    f32x4 rx[4];                         // A staging prefetch

    // prologue: load + stage tile 0
#pragma unroll
    for (int q = 0; q < 4; ++q)
        rx[q] = *(const f32x4*)&X[(size_t)(RM + srow) * CC + sk16 + q * 4];
#pragma unroll
    for (int q = 0; q < 4; ++q)
#pragma unroll
        for (int e = 0; e < 4; ++e)
            At[sk16 + q * 4 + e][srow] = rx[q][e];
    __syncthreads();

    for (int kt = 0; kt < 16; ++kt) {
        // issue A loads for tile kt+1 (in flight during this tile's FMAs)
        if (kt < 15) {
            int kk = (kt + 1) * 32;
#pragma unroll
            for (int q = 0; q < 4; ++q)
                rx[q] = *(const f32x4*)&X[(size_t)(RM + srow) * CC + kk + sk16 + q * 4];
        }
        // FMA phase: strict ascending k; B wave-uniform scalar loads
#pragma unroll 4
        for (int k = 0; k < 32; ++k) {
            f32x8 b = *(const f32x8*)&wcol[(size_t)(kt * 32 + k) * CC];
            f32x4 a = *(const f32x4*)&At[k][lane * 4];
#pragma unroll
            for (int i = 0; i < 4; ++i)
#pragma unroll
                for (int e = 0; e < 4; ++e) {
                    acc[i][e]     = __builtin_fmaf(a[i], b[e],     acc[i][e]);
                    acc[i][4 + e] = __builtin_fmaf(a[i], b[4 + e], acc[i][4 + e]);
                }
        }
        // swap: stage tile kt+1 (single buffer -> barrier, write, barrier)
        if (kt < 15) {
            __syncthreads();
#pragma unroll
            for (int q = 0; q < 4; ++q)
#pragma unroll
                for (int e = 0; e < 4; ++e)
                    At[sk16 + q * 4 + e][srow] = rx[q][e];
            __syncthreads();
        }
    }

#pragma unroll
    for (int i = 0; i < 4; ++i) {
        size_t base = (size_t)(RM + lane * 4 + i) * CC + CN;
        f32x4 o0 = {acc[i][0], acc[i][1], acc[i][2], acc[i][3]};
        f32x4 o1 = {acc[i][4], acc[i][5], acc[i][6], acc[i][7]};
        *(f32x4*)&H[base]     = o0;
        *(f32x4*)&H[base + 4] = o1;
    }
}

// ----------------------------- LIF (fp32, np-op-exact) ---------------------
// Spike byte: 0x3C (= high byte of fp16 1.0) or 0x00.
__global__ __launch_bounds__(256)
void lif_np(const float* __restrict__ H, unsigned char* __restrict__ S8) {
#pragma clang fp contract(off)
    int g = blockIdx.x * 256 + threadIdx.x;   // 0 .. BNC/4-1
    float v[4] = {0.f, 0.f, 0.f, 0.f};
#pragma unroll
    for (int t = 0; t < TT; ++t) {
        f32x4 h = *(const f32x4*)&H[(size_t)t * BNC + (size_t)g * 4];
        unsigned int pack = 0;
#pragma unroll
        for (int e = 0; e < 4; ++e) {
            float d  = h[e] - v[e];          // rounded sub (np: x - (v-0))
            float d2 = d * 0.5f;             // exact (np: /2.0)
            v[e] = v[e] + d2;                // rounded add
            bool sp = v[e] >= 1.0f;
            if (sp) { pack |= 0x3Cu << (8 * e); v[e] = 0.0f; }
        }
        *(unsigned int*)&S8[(size_t)t * BNC + (size_t)g * 4] = pack;
    }
}

// ---------------------------------------------------------------- GEMM2 ----
// O[m][p] = sum_o S[m][o] * W2[p][o]. fp16 MFMA; spikes exact in fp16.
__global__ __launch_bounds__(256)
void gemm2_f16(const unsigned char* __restrict__ S8, const float* __restrict__ W,
               float* __restrict__ O) {
    __shared__ _Float16 As[128][LDK], Bs[128][LDK];

    const int tid  = threadIdx.x;
    const int RM   = blockIdx.x * 128;
    const int CN   = blockIdx.y * 128;
    const int lane = tid & 63;
    const int wv   = tid >> 6;
    const int wr   = (wv >> 1) * 64;
    const int wc   = (wv & 1) * 64;
    const int r15  = lane & 15;
    const int kg   = lane >> 4;

    f32x4 acc[4][4] = {};

    for (int k0 = 0; k0 < CC; k0 += 32) {
        __syncthreads();
#pragma unroll
        for (int j = 0; j < 2; ++j) {
            int id  = tid + 256 * j;
            int row = id >> 2;
            int c8  = (id & 3) * 8;
            unsigned long long v =
                *(const unsigned long long*)&S8[(size_t)(RM + row) * CC + k0 + c8];
            ushort8 u;
#pragma unroll
            for (int e = 0; e < 8; ++e)
                u[e] = (unsigned short)(((v >> (8 * e)) & 0xFFull) << 8);
            *(ushort8*)&As[row][c8] = u;
        }
#pragma unroll
        for (int j = 0; j < 4; ++j) {
            int id  = tid + 256 * j;
            int row = id >> 3;
            int c4  = (id & 7) * 4;
            f32x4 v = *(const f32x4*)&W[(size_t)(CN + row) * CC + k0 + c4];
            half4v hv;
#pragma unroll
            for (int e = 0; e < 4; ++e) hv[e] = (_Float16)v[e];
            *(half4v*)&Bs[row][c4] = hv;
        }
        __syncthreads();

        half8 a[4], b[4];
#pragma unroll
        for (int i = 0; i < 4; ++i) {
            a[i] = *(const half8*)&As[wr + i * 16 + r15][kg * 8];
            b[i] = *(const half8*)&Bs[wc + i * 16 + r15][kg * 8];
        }
#pragma unroll
        for (int i = 0; i < 4; ++i)
#pragma unroll
            for (int j = 0; j < 4; ++j)
                acc[i][j] = __builtin_amdgcn_mfma_f32_16x16x32_f16(a[i], b[j], acc[i][j], 0, 0, 0);
    }

#pragma unroll
    for (int i = 0; i < 4; ++i)
#pragma unroll
        for (int j = 0; j < 4; ++j)
#pragma unroll
            for (int r = 0; r < 4; ++r) {
                int gm = RM + wr + i * 16 + kg * 4 + r;
                int gn = CN + wc + j * 16 + r15;
                O[(size_t)gm * CC + gn] = acc[i][j][r];
            }
}

// -------------------------------------------------------------- launch -----
extern "C" void kernel_launch(void* const* d_in, const int* in_sizes, int n_in,
                              void* d_out, int out_size, void* d_ws, size_t ws_size,
                              hipStream_t stream) {
    const float* x  = (const float*)d_in[0];
    const float* W1 = (const float*)d_in[1];
    const float* W2 = (const float*)d_in[2];
    float* out = (float*)d_out;

    float*         h  = out;                                   // fp32 h in d_out
    unsigned char* s8 = (unsigned char*)d_ws;                  // spikes, 16 MB
    float*         wt = (float*)((char*)d_ws + (size_t)BNC);   // Wt, 1 MB

    dim3 gt(CC / 64, CC / 64);       // (8, 8)
    transpose_w<<<gt, 256, 0, stream>>>(W1, wt);

    dim3 g1(MTOT / 256, CC / 64);    // (128, 8) = 1024 blocks = 4/CU
    gemm1_v19<<<g1, 512, 0, stream>>>(x, wt, h);

    lif_np<<<BNC / 4 / 256, 256, 0, stream>>>(h, s8);

    dim3 g2(MTOT / 128, CC / 128);   // (256, 4)
    gemm2_f16<<<g2, 256, 0, stream>>>(s8, W2, out);
}